// Round 1
// 240.177 us; speedup vs baseline: 1.0611x; 1.0611x over previous
//
#include <hip/hip_runtime.h>

// out[b,s,d] = alpha*sum_{j=1..P} beta^{j-1} x[b,s-j,d] + pf[d] + pb[((s>>5)-d)&31]
//
// READ-ONCE version. Previous kernel re-read x twice in pass B (xt + lagged xl),
// ~240 MB of LLC traffic sharing the load path with the 269 MB HBM stream ->
// combined ~5.4 TB/s memory-system ceiling at 94.6 us. Here each thread keeps its
// chunk's 16 float4 in registers (64 VGPR), and the lagged stream x[s-P] (= chunk
// c-8, since P=128=8*CL) is obtained by an intra-wave shuffle: chunks are remapped
// c = (lane>>3)*8 + wave so that chunk c-8 lives exactly 8 lanes down -> shfl_up(8).
// HBM traffic becomes the irreducible 134 MB in + 134 MB out, zero cache re-reads.
// Occupancy drops to 4 waves/SIMD (launch_bounds 512,4 caps VGPR at 128) -- still
// ~256 KB of loads in flight per CU, far beyond the ~10 KB needed to saturate HBM.
// Numerics are bit-identical to the previous passing kernel (same values, same FMA
// order; shuffled xl has the same bits the re-read had).

typedef float f32x4 __attribute__((ext_vector_type(4)));

constexpr int S    = 1024;
constexpr int D    = 32;
constexpr int CL   = 16;              // 16-runs stay inside one 32-block => s>>5 const
constexpr int NCH  = S / CL;          // 64 chunks
constexpr int LAG  = 8;               // P / CL
constexpr int NTHR = NCH * (D / 4);   // 512

__global__ __launch_bounds__(NTHR, 4)
void attn_pred_kernel(const float* __restrict__ x,
                      const float* __restrict__ alpha_p,
                      const float* __restrict__ beta_p,
                      const float* __restrict__ pos_fwd,
                      const float* __restrict__ pos_bwd,
                      const int*   __restrict__ past_p,
                      float* __restrict__ out)
{
    __shared__ f32x4 sA[NCH][D / 4];  // 4 KiB: pure chunk sums
    __shared__ f32x4 sC[NCH][D / 4];  // 4 KiB: exclusive carries

    const int tid  = threadIdx.x;
    const int b    = blockIdx.x;
    const int lane = tid & 63;
    const int wv   = tid >> 6;        // wave 0..7
    const int g    = lane >> 3;       // lag-group 0..7 within wave
    const int dg   = lane & 7;        // float4 group over d (coalescing unchanged:
                                      // each 8-lane group still covers 128 B)
    const int c    = g * 8 + wv;      // chunk 0..63; chunk c-LAG == lane-8, same wave
    const int s0   = c * CL;

    const float alpha = alpha_p[0];
    const float beta  = beta_p[0];
    const int   P     = past_p[0];    // 128

    // beta^P by squaring (double), beta^CL by 4 squarings
    double bb = (double)beta, bpd = 1.0;
    for (int e = P; e; e >>= 1) { if (e & 1) bpd *= bb; bb *= bb; }
    const float bP = (float)bpd;
    double b16 = (double)beta;
    for (int i = 0; i < 4; ++i) b16 *= b16;
    const float bCL = (float)b16;     // beta^16

    const f32x4* xg = reinterpret_cast<const f32x4*>(x) + (size_t)b * S * (D / 4) + dg;

    // ---- pass A: load chunk ONCE into registers; decayed chunk sum A ----
    f32x4 xr[CL];                     // 64 VGPRs, statically indexed (full unroll)
    #pragma unroll
    for (int i = 0; i < CL; ++i)
        xr[i] = xg[(s0 + i) * (D / 4)];

    f32x4 A = {0.f, 0.f, 0.f, 0.f};
    #pragma unroll
    for (int i = 0; i < CL; ++i) {
        A.x = fmaf(beta, A.x, xr[i].x);
        A.y = fmaf(beta, A.y, xr[i].y);
        A.z = fmaf(beta, A.z, xr[i].z);
        A.w = fmaf(beta, A.w, xr[i].w);
    }
    sA[c][dg] = A;
    __syncthreads();

    // ---- scan (8 threads, one per dg): exclusive carries over 64 chunks ----
    if (tid < D / 4) {
        f32x4 run = {0.f, 0.f, 0.f, 0.f};
        for (int cc = 0; cc < NCH; ++cc) {
            sC[cc][tid] = run;
            const f32x4 Ac = sA[cc][tid];
            f32x4 z;
            if (cc >= LAG) {
                const f32x4 Al = sA[cc - LAG][tid];
                z.x = alpha * fmaf(-bP, Al.x, Ac.x);
                z.y = alpha * fmaf(-bP, Al.y, Ac.y);
                z.z = alpha * fmaf(-bP, Al.z, Ac.z);
                z.w = alpha * fmaf(-bP, Al.w, Ac.w);
            } else {
                z.x = alpha * Ac.x; z.y = alpha * Ac.y;
                z.z = alpha * Ac.z; z.w = alpha * Ac.w;
            }
            run.x = fmaf(bCL, run.x, z.x);
            run.y = fmaf(bCL, run.y, z.y);
            run.z = fmaf(bCL, run.z, z.z);
            run.w = fmaf(bCL, run.w, z.w);
        }
    }
    __syncthreads();
    f32x4 y = sC[c][dg];

    // ---- positional bias (s>>5 == c>>1, constant over the chunk) ----
    const int d0 = dg * 4;
    const int q  = c >> 1;
    const f32x4 pf = reinterpret_cast<const f32x4*>(pos_fwd)[dg];
    f32x4 add;
    add.x = pf.x + pos_bwd[(q - (d0 + 0)) & (D - 1)];
    add.y = pf.y + pos_bwd[(q - (d0 + 1)) & (D - 1)];
    add.z = pf.z + pos_bwd[(q - (d0 + 2)) & (D - 1)];
    add.w = pf.w + pos_bwd[(q - (d0 + 3)) & (D - 1)];

    // ---- pass B: emit 16 outputs; lagged x via intra-wave shuffle, zero re-reads ----
    const float aP   = alpha * bP;            // alpha*beta^P
    const float m    = (g > 0) ? -aP : 0.f;   // c >= LAG <=> g >= 1; lanes 0..7 get
                                              // their own (finite) value from shfl_up,
                                              // killed by m=0
    f32x4* og = reinterpret_cast<f32x4*>(out) + ((size_t)b * S + s0) * (D / 4) + dg;
    #pragma unroll
    for (int i = 0; i < CL; ++i) {
        f32x4 o;
        o.x = y.x + add.x; o.y = y.y + add.y;
        o.z = y.z + add.z; o.w = y.w + add.w;
        __builtin_nontemporal_store(o, &og[i * (D / 4)]);

        f32x4 xl;
        xl.x = __shfl_up(xr[i].x, 8);
        xl.y = __shfl_up(xr[i].y, 8);
        xl.z = __shfl_up(xr[i].z, 8);
        xl.w = __shfl_up(xr[i].w, 8);

        y.x = fmaf(beta, y.x, fmaf(alpha, xr[i].x, m * xl.x));
        y.y = fmaf(beta, y.y, fmaf(alpha, xr[i].y, m * xl.y));
        y.z = fmaf(beta, y.z, fmaf(alpha, xr[i].z, m * xl.z));
        y.w = fmaf(beta, y.w, fmaf(alpha, xr[i].w, m * xl.w));
    }
}

extern "C" void kernel_launch(void* const* d_in, const int* in_sizes, int n_in,
                              void* d_out, int out_size, void* d_ws, size_t ws_size,
                              hipStream_t stream) {
    const float* x  = (const float*)d_in[0];
    const float* al = (const float*)d_in[1];
    const float* be = (const float*)d_in[2];
    const float* pf = (const float*)d_in[3];
    const float* pb = (const float*)d_in[4];
    const int*   ps = (const int*)d_in[5];
    float* out = (float*)d_out;

    const int B = in_sizes[0] / (S * D);   // 1024
    attn_pred_kernel<<<dim3(B), NTHR, 0, stream>>>(x, al, be, pf, pb, ps, out);
}